// Round 20
// baseline (101.908 us; speedup 1.0000x reference)
//
#include <hip/hip_runtime.h>
#include <math.h>

// BEV deformable attention encoder, layer l = L-1 only.
// Round 20: dispatch 3 -> 2. proj folded into attn: each attn block owns the
// 64ch x 16px inner slab its h contributes; computes the 256x64 @ 64x16
// partial projection from LDS (inner_blk aliased onto dead q_lds -> no LDS
// growth) and atomicAdds onto a zeroed out (hipMemsetAsync per call ->
// replay-idempotent; 8-partial fp order nondet ~1e-6 << threshold). Bias
// added by h==7 blocks. off_cpb = r19 verbatim (r14/r16/r19 all ~92us:
// every pipe-level lever A/B'd null; this is the last structural lever).

#define NP 1600   // 40*40 query pixels
#define NJ 100    // 10*10 kv pixels

typedef _Float16 f16x8 __attribute__((ext_vector_type(8)));
typedef _Float16 f16x4 __attribute__((ext_vector_type(4)));
typedef _Float16 f16x2 __attribute__((ext_vector_type(2)));
typedef float  f32x4  __attribute__((ext_vector_type(4)));
typedef float  f32x2  __attribute__((ext_vector_type(2)));

template<int CTRL>
__device__ __forceinline__ float dpp_add(float x) {
  int y = __builtin_amdgcn_update_dpp(0, __builtin_bit_cast(int, x),
                                      CTRL, 0xf, 0xf, true);
  return x + __builtin_bit_cast(float, y);
}

// ------ fused: LDS-staged-q dw 6x6 s4 + gelu + pw + tanh + grid + sample
//        + k/v conv + fp16 layer-1 tables + CPB MFMA. One block per gj;
//        XCD-remapped: g = b&7, j = b>>3. (r19 verbatim) -------------------
__global__ __launch_bounds__(256, 4) void k_off_cpb(
    const float* __restrict__ x, const float* __restrict__ wq,
    const float* __restrict__ wdw,
    const float* __restrict__ bdw, const float* __restrict__ wo2,
    const float* __restrict__ wk, const float* __restrict__ wv,
    const float* __restrict__ w0, const float* __restrict__ b0,
    const float* __restrict__ w1, const float* __restrict__ b1v,
    const float* __restrict__ cw2, const float* __restrict__ b2,
    float* __restrict__ kout, float* __restrict__ vout_t,
    _Float16* __restrict__ bias16) {
  __shared__ float x_lds[36][36];   // [tap][ci], 144B rows (16B-aligned)
  __shared__ float psum[4][72];
  __shared__ float su_l[40];
  __shared__ float sv_l[40];
  __shared__ _Float16 a16[40][72];
  __shared__ _Float16 c16[40][72];
  int b = blockIdx.x;
  int g = b & 7;          // XCD-aware: one group per XCD L2
  int j = b >> 3;         // 0..99
  int gj = g * 100 + j;   // semantic column id (output layout unchanged)
  int t = threadIdx.x;
  int lane = t & 63;
  int wv_id = t >> 6;
  int oy = j / 10, ox = j - (j / 10) * 10;
  int row = lane & 15;
  int kgrp = lane >> 4;

  // stage x patch: (ci, tap) with tap fast-varying (coalesced runs of 6)
  for (int idx = t; idx < 1152; idx += 256) {
    int ci = idx / 36, tap = idx - (idx / 36) * 36;
    int ky = tap / 6, kx = tap - (tap / 6) * 6;
    int iy = oy * 4 - 1 + ky;
    int ix = ox * 4 - 1 + kx;
    float v = 0.f;
    if (iy >= 0 && iy < 40 && ix >= 0 && ix < 40)
      v = x[(g * 32 + ci) * NP + iy * 40 + ix];
    x_lds[tap][ci] = v;
  }
  __syncthreads();

  // dw-conv partials, q from b128 LDS broadcasts
  {
    float wqreg[32];
    const float* wqr = wq + (size_t)(g * 64 + lane) * 32;
#pragma unroll
    for (int q4 = 0; q4 < 8; ++q4) {
      f32x4 a = *(const f32x4*)(wqr + q4 * 4);
#pragma unroll
      for (int e = 0; e < 4; ++e) wqreg[q4 * 4 + e] = a[e];
    }
    float acc = 0.f;
#pragma unroll
    for (int tu = 0; tu < 9; ++tu) {
      int tt = wv_id * 9 + tu;
      float qv = 0.f;
#pragma unroll
      for (int q4 = 0; q4 < 8; ++q4) {
        f32x4 xv = *(const f32x4*)&x_lds[tt][q4 * 4];   // b128 broadcast
#pragma unroll
        for (int e = 0; e < 4; ++e)
          qv = fmaf(wqreg[q4 * 4 + e], xv[e], qv);
      }
      acc = fmaf(wdw[lane * 36 + tt], qv, acc);
    }
    psum[wv_id][lane] = acc;
  }
  __syncthreads();

  // wave 0: gelu -> pw -> tanh*4 -> grid -> sample -> k/v conv
  if (wv_id == 0) {
    float accd = psum[0][lane] + psum[1][lane] + psum[2][lane] + psum[3][lane]
               + bdw[lane];
    float od = 0.5f * accd * (1.0f + erff(accd * 0.70710678118654752440f));
    float px = wo2[lane] * od, py = wo2[64 + lane] * od;
#pragma unroll
    for (int m = 1; m < 64; m <<= 1) {
      px += __shfl_xor(px, m);
      py += __shfl_xor(py, m);
    }
    float ax = tanhf(px) * 4.f;
    float ay = tanhf(py) * 4.f;
    float vx = (float)ox + ax;
    float vy = (float)oy + ay;
    float g0 = 2.f * vx / 9.f - 1.f;
    float g1 = 2.f * vy / 9.f - 1.f;
    if (lane < 40) {
      float qc = (float)lane * (2.f / 39.f) - 1.f;
      float u = qc - g0;
      float vv2 = qc - g1;
      su_l[lane] = copysignf(log1pf(fabsf(u)), u);
      sv_l[lane] = copysignf(log1pf(fabsf(vv2)), vv2);
    }
    float gx = ((g0 + 1.f) * 40.f - 1.f) * 0.5f;
    float gy = ((g1 + 1.f) * 40.f - 1.f) * 0.5f;
    float x0f = floorf(gx), y0f = floorf(gy);
    float wx = gx - x0f, wy = gy - y0f;
    bool mx0 = (x0f >= 0.f) && (x0f <= 39.f);
    bool mx1 = (x0f + 1.f >= 0.f) && (x0f + 1.f <= 39.f);
    bool my0 = (y0f >= 0.f) && (y0f <= 39.f);
    bool my1 = (y0f + 1.f >= 0.f) && (y0f + 1.f <= 39.f);
    int ix0 = (int)fminf(fmaxf(x0f, 0.f), 39.f);
    int ix1 = (int)fminf(fmaxf(x0f + 1.f, 0.f), 39.f);
    int iy0 = (int)fminf(fmaxf(y0f, 0.f), 39.f);
    int iy1 = (int)fminf(fmaxf(y0f + 1.f, 0.f), 39.f);
    float w00 = (1.f - wx) * (1.f - wy) * ((mx0 && my0) ? 1.f : 0.f);
    float w10 = wx * (1.f - wy) * ((mx1 && my0) ? 1.f : 0.f);
    float w01 = (1.f - wx) * wy * ((mx0 && my1) ? 1.f : 0.f);
    float w11 = wx * wy * ((mx1 && my1) ? 1.f : 0.f);
    int b00 = iy0 * 40 + ix0, b10 = iy0 * 40 + ix1;
    int b01 = iy1 * 40 + ix0, b11 = iy1 * 40 + ix1;
    float kvc = 0.f;
    if (lane < 32) {
      const float* xc = x + (g * 32 + lane) * NP;
      kvc = w00 * xc[b00] + w10 * xc[b10] + w01 * xc[b01] + w11 * xc[b11];
    }
    const float* wkr = wk + (g * 64 + lane) * 32;
    const float* wvr = wv + (g * 64 + lane) * 32;
    float wkreg[32], wvreg[32];
#pragma unroll
    for (int q4 = 0; q4 < 8; ++q4) {
      f32x4 a = *(const f32x4*)(wkr + q4 * 4);
      f32x4 bq = *(const f32x4*)(wvr + q4 * 4);
#pragma unroll
      for (int e = 0; e < 4; ++e) { wkreg[q4 * 4 + e] = a[e]; wvreg[q4 * 4 + e] = bq[e]; }
    }
    float kacc = 0.f, vacc = 0.f;
#pragma unroll
    for (int c = 0; c < 32; ++c) {
      float kvb = __shfl(kvc, c);
      kacc = fmaf(wkreg[c], kvb, kacc);
      vacc = fmaf(wvreg[c], kvb, vacc);
    }
    kout[(g * 64 + lane) * 100 + j] = kacc;
    vout_t[(size_t)gj * 64 + lane] = vacc;     // transposed, coalesced
  }
  __syncthreads();

  // fp16 layer-1 tables (all waves)
  for (int idx = t; idx < 2560; idx += 256) {
    int xi = idx >> 6, kk = idx & 63;
    a16[xi][kk] = (_Float16)fmaf(w0[2 * kk], su_l[xi], b0[kk]);
    c16[xi][kk] = (_Float16)(w0[2 * kk + 1] * sv_l[xi]);
  }

  // cpb MFMA: B frags + per-wave 25 tiles
  f16x8 B[4][2];
#pragma unroll
  for (int ct = 0; ct < 4; ++ct)
#pragma unroll
    for (int s = 0; s < 2; ++s)
#pragma unroll
      for (int e = 0; e < 8; ++e)
        B[ct][s][e] = (_Float16)w1[(ct * 16 + row) * 64 + s * 32 + kgrp * 8 + e];
  float b1c[4], w2c[4];
#pragma unroll
  for (int ct = 0; ct < 4; ++ct) {
    b1c[ct] = b1v[ct * 16 + row];
    w2c[ct] = cw2[ct * 16 + row];
  }
  float bb = b2[0];
  _Float16* outp = bias16 + (size_t)gj * 1600;
  __syncthreads();

  int it0 = wv_id * 25;
  int iy = wv_id * 10;
  int ix = row;
  f16x8 zero8 = {};
  for (int it = it0; it < it0 + 25; ++it) {
    f32x4 acc[4];
#pragma unroll
    for (int ct = 0; ct < 4; ++ct) {
      acc[ct][0] = 0.f; acc[ct][1] = 0.f; acc[ct][2] = 0.f; acc[ct][3] = 0.f;
    }
#pragma unroll
    for (int s = 0; s < 2; ++s) {
      f16x8 av = *(const f16x8*)&a16[ix][s * 32 + kgrp * 8];
      f16x8 cv = *(const f16x8*)&c16[iy][s * 32 + kgrp * 8];
      f16x8 A = __builtin_elementwise_max(av + cv, zero8);
#pragma unroll
      for (int ct = 0; ct < 4; ++ct)
        acc[ct] = __builtin_amdgcn_mfma_f32_16x16x32_f16(A, B[ct][s], acc[ct], 0, 0, 0);
    }
    float part[4];
#pragma unroll
    for (int ri = 0; ri < 4; ++ri) {
      float s2 = 0.f;
#pragma unroll
      for (int ct = 0; ct < 4; ++ct) {
        float val = acc[ct][ri] + b1c[ct];
        s2 = fmaf(w2c[ct], fmaxf(val, 0.f), s2);
      }
      part[ri] = s2;
    }
#pragma unroll
    for (int ri = 0; ri < 4; ++ri) {
      part[ri] = dpp_add<0xB1>(part[ri]);    // quad_perm [1,0,3,2]
      part[ri] = dpp_add<0x4E>(part[ri]);    // quad_perm [2,3,0,1]
      part[ri] = dpp_add<0x141>(part[ri]);   // row_half_mirror
      part[ri] = dpp_add<0x140>(part[ri]);   // row_mirror
    }
    if (row == 0) {
      f16x4 o;
      o[0] = (_Float16)(part[0] + bb); o[1] = (_Float16)(part[1] + bb);
      o[2] = (_Float16)(part[2] + bb); o[3] = (_Float16)(part[3] + bb);
      *(f16x4*)(outp + it * 16 + kgrp * 4) = o;
    }
    ix += 16;
    if (ix >= 40) { ix -= 40; ++iy; }
  }
}

// ------ fused attention + partial output projection (atomic accumulate) ----
// One block per (h, 16-i tile). After PV, inner slab lives in LDS (aliased
// onto dead q_lds); block computes its 256x64 @ 64x16 proj partial and
// atomicAdds into out (zeroed per call). h==7 blocks add the bias.
__global__ __launch_bounds__(256) void k_attn(
    const float* __restrict__ x, const float* __restrict__ wq,
    const float* __restrict__ k, const float* __restrict__ v_t,
    const _Float16* __restrict__ bias16,
    const float* __restrict__ wout, const float* __restrict__ bout,
    float* __restrict__ out) {
  __shared__ float v_lds[100][68];
  __shared__ float s_lds[16][100];
  __shared__ float q_lds[64][20];   // 1280 floats; reused as inner_blk[16][68]
  __shared__ float x_tile[32][16];
  int h = blockIdx.x / 100;
  int i0 = (blockIdx.x - h * 100) * 16;
  int t = threadIdx.x;
  for (int idx = t; idx < 6400; idx += 256) {
    int j = idx >> 6, d = idx & 63;
    v_lds[j][d] = v_t[(size_t)h * 6400 + idx];
  }
  for (int idx = t; idx < 512; idx += 256) {
    int ci = idx >> 4, i = idx & 15;
    x_tile[ci][i] = x[(h * 32 + ci) * NP + i0 + i];
  }
  __syncthreads();
  {
    int d = t & 63;
    int i4 = t >> 6;
    f32x4 wr[8];
#pragma unroll
    for (int qq = 0; qq < 8; ++qq)
      wr[qq] = *(const f32x4*)(wq + (size_t)(h * 64 + d) * 32 + qq * 4);
#pragma unroll
    for (int ii = 0; ii < 4; ++ii) {
      int i = i4 * 4 + ii;
      float acc = 0.f;
#pragma unroll
      for (int ci = 0; ci < 32; ++ci)
        acc = fmaf(wr[ci >> 2][ci & 3], x_tile[ci][i], acc);   // broadcast
      q_lds[d][i] = acc;
    }
  }
  __syncthreads();
  if (t < 200) {
    int ib = (t / 25) * 2, jb = (t % 25) * 4;
    const float* kp = k + h * 64 * 100 + jb;
    float a[2][4];
#pragma unroll
    for (int ii = 0; ii < 2; ++ii)
#pragma unroll
      for (int jj = 0; jj < 4; ++jj) a[ii][jj] = 0.f;
#pragma unroll 8
    for (int d = 0; d < 64; ++d) {
      f32x2 qv = *(const f32x2*)&q_lds[d][ib];
      f32x4 kv4 = *(const f32x4*)(kp + d * 100);
#pragma unroll
      for (int ii = 0; ii < 2; ++ii)
#pragma unroll
        for (int jj = 0; jj < 4; ++jj)
          a[ii][jj] = fmaf(qv[ii], kv4[jj], a[ii][jj]);
    }
    const _Float16* bcol = bias16 + (size_t)h * 100 * 1600;
#pragma unroll
    for (int jj = 0; jj < 4; ++jj) {
      f16x2 bv = *(const f16x2*)(bcol + (size_t)(jb + jj) * 1600 + i0 + ib);
#pragma unroll
      for (int ii = 0; ii < 2; ++ii)
        s_lds[ib + ii][jb + jj] = fmaf(a[ii][jj], 0.125f, (float)bv[ii]);
    }
  }
  __syncthreads();
  {
    int i = t >> 4, sub = t & 15;
    float m = -1e30f;
    for (int j = sub; j < 100; j += 16) m = fmaxf(m, s_lds[i][j]);
#pragma unroll
    for (int off = 1; off < 16; off <<= 1) m = fmaxf(m, __shfl_xor(m, off));
    float sum = 0.f;
    for (int j = sub; j < 100; j += 16) {
      float e = expf(s_lds[i][j] - m);
      s_lds[i][j] = e;
      sum += e;
    }
#pragma unroll
    for (int off = 1; off < 16; off <<= 1) sum += __shfl_xor(sum, off);
    float inv = 1.f / sum;
    for (int j = sub; j < 100; j += 16) s_lds[i][j] *= inv;
  }
  __syncthreads();
  float (*inner_blk)[68] = (float(*)[68])&q_lds[0][0];   // q_lds dead
  {
    int i = t & 15, db = (t >> 4) * 4;
    float acc[4];
#pragma unroll
    for (int dd = 0; dd < 4; ++dd) acc[dd] = 0.f;
    for (int jc = 0; jc < 25; ++jc) {
      f32x4 sv = *(const f32x4*)&s_lds[i][jc * 4];
#pragma unroll
      for (int jj = 0; jj < 4; ++jj) {
        f32x4 vv = *(const f32x4*)&v_lds[jc * 4 + jj][db];
#pragma unroll
        for (int dd = 0; dd < 4; ++dd)
          acc[dd] = fmaf(sv[jj], vv[dd], acc[dd]);
      }
    }
    f32x4 o4;
#pragma unroll
    for (int dd = 0; dd < 4; ++dd) o4[dd] = acc[dd];
    *(f32x4*)&inner_blk[i][db] = o4;   // [p_loc][c], 16B-aligned rows
  }
  __syncthreads();
  // proj partial: thread = (o_grp = t>>4 -> 16 couts, p_loc = t&15)
  {
    int o_grp = t >> 4, p_loc = t & 15;
    int p = i0 + p_loc;
    const float* ib = &inner_blk[p_loc][0];
    float po[16];
#pragma unroll
    for (int oo = 0; oo < 16; ++oo) po[oo] = 0.f;
#pragma unroll 4
    for (int c4 = 0; c4 < 16; ++c4) {
      f32x4 iv = *(const f32x4*)(ib + c4 * 4);
#pragma unroll
      for (int oo = 0; oo < 16; ++oo) {
        f32x4 w4 = *(const f32x4*)(wout + (size_t)(o_grp * 16 + oo) * 512
                                   + h * 64 + c4 * 4);
#pragma unroll
        for (int e = 0; e < 4; ++e)
          po[oo] = fmaf(w4[e], iv[e], po[oo]);
      }
    }
    if (h == 7) {
#pragma unroll
      for (int oo = 0; oo < 16; ++oo) po[oo] += bout[o_grp * 16 + oo];
    }
#pragma unroll
    for (int oo = 0; oo < 16; ++oo)
      atomicAdd(&out[(size_t)(o_grp * 16 + oo) * NP + p], po[oo]);
  }
}

extern "C" void kernel_launch(void* const* d_in, const int* in_sizes, int n_in,
                              void* d_out, int out_size, void* d_ws, size_t ws_size,
                              hipStream_t stream) {
  int L = in_sizes[1] / (512 * 32);
  int l = L - 1;
  const float* x      = (const float*)d_in[0];
  const float* wq     = (const float*)d_in[1]  + (size_t)l * 512 * 32;
  const float* wk     = (const float*)d_in[2]  + (size_t)l * 512 * 32;
  const float* wv     = (const float*)d_in[3]  + (size_t)l * 512 * 32;
  const float* w_off1 = (const float*)d_in[4]  + (size_t)l * 64 * 36;
  const float* b_off1 = (const float*)d_in[5]  + (size_t)l * 64;
  const float* w_off2 = (const float*)d_in[6]  + (size_t)l * 2 * 64;
  const float* cpb_w0 = (const float*)d_in[7]  + (size_t)l * 64 * 2;
  const float* cpb_b0 = (const float*)d_in[8]  + (size_t)l * 64;
  const float* cpb_w1 = (const float*)d_in[9]  + (size_t)l * 64 * 64;
  const float* cpb_b1 = (const float*)d_in[10] + (size_t)l * 64;
  const float* cpb_w2 = (const float*)d_in[11] + (size_t)l * 64;
  const float* cpb_b2 = (const float*)d_in[12] + (size_t)l * 1;
  const float* w_out  = (const float*)d_in[13] + (size_t)l * 256 * 512;
  const float* b_out  = (const float*)d_in[14] + (size_t)l * 256;
  float* out = (float*)d_out;

  float* ws = (float*)d_ws;
  float*    k_ws    = ws;               // 51200
  float*    vt_ws   = ws + 51200;       // 51200 (transposed [gj][c])
  _Float16* bias16  = (_Float16*)(ws + 102400);  // 1280000 halves = 640000 f
  // (inner buffer eliminated)

  hipMemsetAsync(out, 0, (size_t)out_size * sizeof(float), stream);
  k_off_cpb<<<800, 256, 0, stream>>>(x, wq, w_off1, b_off1, w_off2, wk, wv,
                                     cpb_w0, cpb_b0, cpb_w1, cpb_b1, cpb_w2,
                                     cpb_b2, k_ws, vt_ws, bias16);
  k_attn<<<800, 256, 0, stream>>>(x, wq, k_ws, vt_ws, bias16,
                                  w_out, b_out, out);
}

// Round 21
// 91.842 us; speedup vs baseline: 1.1096x; 1.1096x over previous
//
#include <hip/hip_runtime.h>
#include <math.h>

// BEV deformable attention encoder, layer l = L-1 only.
// FINAL (r21 = r19 verbatim revert): best-proven state, 91.9us (measured
// 91.9/92.0/91.9 across r14/r16/r19). r20's proj-fold refuted (VGPR 116 ->
// occ 15%, attn 28->62us). Session ledger 337.8 -> 91.9us (3.7x):
//   - CPB bias MLP (95% of FLOPs) via fp16 MFMA + DPP epilogue
//   - offset net fused + XCD-aware block mapping + fp16 bias buffer
//   - q never materialized (recomputed from x+wq via LDS broadcasts)
//   - occupancy/latency levers A/B'd exhaustively; residual ~92us is
//     phase-latency + launch overhead at this tiny problem size, not a
//     HW roofline (all pipes <40%, HBM <3%).

#define NP 1600   // 40*40 query pixels
#define NJ 100    // 10*10 kv pixels

typedef _Float16 f16x8 __attribute__((ext_vector_type(8)));
typedef _Float16 f16x4 __attribute__((ext_vector_type(4)));
typedef _Float16 f16x2 __attribute__((ext_vector_type(2)));
typedef float  f32x4  __attribute__((ext_vector_type(4)));
typedef float  f32x2  __attribute__((ext_vector_type(2)));

template<int CTRL>
__device__ __forceinline__ float dpp_add(float x) {
  int y = __builtin_amdgcn_update_dpp(0, __builtin_bit_cast(int, x),
                                      CTRL, 0xf, 0xf, true);
  return x + __builtin_bit_cast(float, y);
}

// ------ fused: LDS-staged-q dw 6x6 s4 + gelu + pw + tanh + grid + sample
//        + k/v conv + fp16 layer-1 tables + CPB MFMA. One block per gj;
//        XCD-remapped: g = b&7, j = b>>3. --------------------------------
__global__ __launch_bounds__(256, 4) void k_off_cpb(
    const float* __restrict__ x, const float* __restrict__ wq,
    const float* __restrict__ wdw,
    const float* __restrict__ bdw, const float* __restrict__ wo2,
    const float* __restrict__ wk, const float* __restrict__ wv,
    const float* __restrict__ w0, const float* __restrict__ b0,
    const float* __restrict__ w1, const float* __restrict__ b1v,
    const float* __restrict__ cw2, const float* __restrict__ b2,
    float* __restrict__ kout, float* __restrict__ vout_t,
    _Float16* __restrict__ bias16) {
  __shared__ float x_lds[36][36];   // [tap][ci], 144B rows (16B-aligned)
  __shared__ float psum[4][72];
  __shared__ float su_l[40];
  __shared__ float sv_l[40];
  __shared__ _Float16 a16[40][72];
  __shared__ _Float16 c16[40][72];
  int b = blockIdx.x;
  int g = b & 7;          // XCD-aware: one group per XCD L2
  int j = b >> 3;         // 0..99
  int gj = g * 100 + j;   // semantic column id (output layout unchanged)
  int t = threadIdx.x;
  int lane = t & 63;
  int wv_id = t >> 6;
  int oy = j / 10, ox = j - (j / 10) * 10;
  int row = lane & 15;
  int kgrp = lane >> 4;

  // ---- stage x patch: (ci, tap) with tap FAST-varying -> global reads are
  //      runs of 6 contiguous floats (coalesced); LDS write [tap][ci].
  for (int idx = t; idx < 1152; idx += 256) {
    int ci = idx / 36, tap = idx - (idx / 36) * 36;
    int ky = tap / 6, kx = tap - (tap / 6) * 6;
    int iy = oy * 4 - 1 + ky;
    int ix = ox * 4 - 1 + kx;
    float v = 0.f;
    if (iy >= 0 && iy < 40 && ix >= 0 && ix < 40)
      v = x[(g * 32 + ci) * NP + iy * 40 + ix];
    x_lds[tap][ci] = v;
  }
  __syncthreads();

  // ---- dw-conv partials, q from b128 LDS broadcasts: wave handles taps
  //      wv_id*9..+8; lane = d. ci-ascending fmaf order; OOB rows are zero
  //      -> fmaf(w,0,acc)=acc (bitwise identical).
  {
    float wqreg[32];
    const float* wqr = wq + (size_t)(g * 64 + lane) * 32;
#pragma unroll
    for (int q4 = 0; q4 < 8; ++q4) {
      f32x4 a = *(const f32x4*)(wqr + q4 * 4);
#pragma unroll
      for (int e = 0; e < 4; ++e) wqreg[q4 * 4 + e] = a[e];
    }
    float acc = 0.f;
#pragma unroll
    for (int tu = 0; tu < 9; ++tu) {
      int tt = wv_id * 9 + tu;
      float qv = 0.f;
#pragma unroll
      for (int q4 = 0; q4 < 8; ++q4) {
        f32x4 xv = *(const f32x4*)&x_lds[tt][q4 * 4];   // b128 broadcast
#pragma unroll
        for (int e = 0; e < 4; ++e)
          qv = fmaf(wqreg[q4 * 4 + e], xv[e], qv);
      }
      acc = fmaf(wdw[lane * 36 + tt], qv, acc);
    }
    psum[wv_id][lane] = acc;
  }
  __syncthreads();

  // wave 0: gelu -> pw -> tanh*4 -> grid -> sample -> k/v conv
  if (wv_id == 0) {
    float accd = psum[0][lane] + psum[1][lane] + psum[2][lane] + psum[3][lane]
               + bdw[lane];
    float od = 0.5f * accd * (1.0f + erff(accd * 0.70710678118654752440f));
    float px = wo2[lane] * od, py = wo2[64 + lane] * od;
#pragma unroll
    for (int m = 1; m < 64; m <<= 1) {
      px += __shfl_xor(px, m);
      py += __shfl_xor(py, m);
    }
    float ax = tanhf(px) * 4.f;
    float ay = tanhf(py) * 4.f;
    float vx = (float)ox + ax;
    float vy = (float)oy + ay;
    float g0 = 2.f * vx / 9.f - 1.f;
    float g1 = 2.f * vy / 9.f - 1.f;
    if (lane < 40) {
      float qc = (float)lane * (2.f / 39.f) - 1.f;
      float u = qc - g0;
      float vv2 = qc - g1;
      su_l[lane] = copysignf(log1pf(fabsf(u)), u);
      sv_l[lane] = copysignf(log1pf(fabsf(vv2)), vv2);
    }
    float gx = ((g0 + 1.f) * 40.f - 1.f) * 0.5f;
    float gy = ((g1 + 1.f) * 40.f - 1.f) * 0.5f;
    float x0f = floorf(gx), y0f = floorf(gy);
    float wx = gx - x0f, wy = gy - y0f;
    bool mx0 = (x0f >= 0.f) && (x0f <= 39.f);
    bool mx1 = (x0f + 1.f >= 0.f) && (x0f + 1.f <= 39.f);
    bool my0 = (y0f >= 0.f) && (y0f <= 39.f);
    bool my1 = (y0f + 1.f >= 0.f) && (y0f + 1.f <= 39.f);
    int ix0 = (int)fminf(fmaxf(x0f, 0.f), 39.f);
    int ix1 = (int)fminf(fmaxf(x0f + 1.f, 0.f), 39.f);
    int iy0 = (int)fminf(fmaxf(y0f, 0.f), 39.f);
    int iy1 = (int)fminf(fmaxf(y0f + 1.f, 0.f), 39.f);
    float w00 = (1.f - wx) * (1.f - wy) * ((mx0 && my0) ? 1.f : 0.f);
    float w10 = wx * (1.f - wy) * ((mx1 && my0) ? 1.f : 0.f);
    float w01 = (1.f - wx) * wy * ((mx0 && my1) ? 1.f : 0.f);
    float w11 = wx * wy * ((mx1 && my1) ? 1.f : 0.f);
    int b00 = iy0 * 40 + ix0, b10 = iy0 * 40 + ix1;
    int b01 = iy1 * 40 + ix0, b11 = iy1 * 40 + ix1;
    float kvc = 0.f;
    if (lane < 32) {
      const float* xc = x + (g * 32 + lane) * NP;
      kvc = w00 * xc[b00] + w10 * xc[b10] + w01 * xc[b01] + w11 * xc[b11];
    }
    const float* wkr = wk + (g * 64 + lane) * 32;
    const float* wvr = wv + (g * 64 + lane) * 32;
    float wkreg[32], wvreg[32];
#pragma unroll
    for (int q4 = 0; q4 < 8; ++q4) {
      f32x4 a = *(const f32x4*)(wkr + q4 * 4);
      f32x4 bq = *(const f32x4*)(wvr + q4 * 4);
#pragma unroll
      for (int e = 0; e < 4; ++e) { wkreg[q4 * 4 + e] = a[e]; wvreg[q4 * 4 + e] = bq[e]; }
    }
    float kacc = 0.f, vacc = 0.f;
#pragma unroll
    for (int c = 0; c < 32; ++c) {
      float kvb = __shfl(kvc, c);
      kacc = fmaf(wkreg[c], kvb, kacc);
      vacc = fmaf(wvreg[c], kvb, vacc);
    }
    kout[(g * 64 + lane) * 100 + j] = kacc;
    vout_t[(size_t)gj * 64 + lane] = vacc;     // transposed, coalesced
  }
  __syncthreads();

  // fp16 layer-1 tables (all waves)
  for (int idx = t; idx < 2560; idx += 256) {
    int xi = idx >> 6, kk = idx & 63;
    a16[xi][kk] = (_Float16)fmaf(w0[2 * kk], su_l[xi], b0[kk]);
    c16[xi][kk] = (_Float16)(w0[2 * kk + 1] * sv_l[xi]);
  }

  // cpb MFMA: B frags + per-wave 25 tiles
  f16x8 B[4][2];
#pragma unroll
  for (int ct = 0; ct < 4; ++ct)
#pragma unroll
    for (int s = 0; s < 2; ++s)
#pragma unroll
      for (int e = 0; e < 8; ++e)
        B[ct][s][e] = (_Float16)w1[(ct * 16 + row) * 64 + s * 32 + kgrp * 8 + e];
  float b1c[4], w2c[4];
#pragma unroll
  for (int ct = 0; ct < 4; ++ct) {
    b1c[ct] = b1v[ct * 16 + row];
    w2c[ct] = cw2[ct * 16 + row];
  }
  float bb = b2[0];
  _Float16* outp = bias16 + (size_t)gj * 1600;
  __syncthreads();

  int it0 = wv_id * 25;
  int iy = wv_id * 10;
  int ix = row;
  f16x8 zero8 = {};
  for (int it = it0; it < it0 + 25; ++it) {
    f32x4 acc[4];
#pragma unroll
    for (int ct = 0; ct < 4; ++ct) {
      acc[ct][0] = 0.f; acc[ct][1] = 0.f; acc[ct][2] = 0.f; acc[ct][3] = 0.f;
    }
#pragma unroll
    for (int s = 0; s < 2; ++s) {
      f16x8 av = *(const f16x8*)&a16[ix][s * 32 + kgrp * 8];
      f16x8 cv = *(const f16x8*)&c16[iy][s * 32 + kgrp * 8];
      f16x8 A = __builtin_elementwise_max(av + cv, zero8);
#pragma unroll
      for (int ct = 0; ct < 4; ++ct)
        acc[ct] = __builtin_amdgcn_mfma_f32_16x16x32_f16(A, B[ct][s], acc[ct], 0, 0, 0);
    }
    float part[4];
#pragma unroll
    for (int ri = 0; ri < 4; ++ri) {
      float s2 = 0.f;
#pragma unroll
      for (int ct = 0; ct < 4; ++ct) {
        float val = acc[ct][ri] + b1c[ct];
        s2 = fmaf(w2c[ct], fmaxf(val, 0.f), s2);
      }
      part[ri] = s2;
    }
#pragma unroll
    for (int ri = 0; ri < 4; ++ri) {
      part[ri] = dpp_add<0xB1>(part[ri]);    // quad_perm [1,0,3,2]
      part[ri] = dpp_add<0x4E>(part[ri]);    // quad_perm [2,3,0,1]
      part[ri] = dpp_add<0x141>(part[ri]);   // row_half_mirror
      part[ri] = dpp_add<0x140>(part[ri]);   // row_mirror
    }
    if (row == 0) {
      f16x4 o;
      o[0] = (_Float16)(part[0] + bb); o[1] = (_Float16)(part[1] + bb);
      o[2] = (_Float16)(part[2] + bb); o[3] = (_Float16)(part[3] + bb);
      *(f16x4*)(outp + it * 16 + kgrp * 4) = o;
    }
    ix += 16;
    if (ix >= 40) { ix -= 40; ++iy; }
  }
}

// ---------------- fused attention: LDS-staged q, i-tile 16, 800 blocks -----
__global__ __launch_bounds__(256) void k_attn(
    const float* __restrict__ x, const float* __restrict__ wq,
    const float* __restrict__ k, const float* __restrict__ v_t,
    const _Float16* __restrict__ bias16, float* __restrict__ inner) {
  __shared__ float v_lds[100][68];
  __shared__ float s_lds[16][100];
  __shared__ float q_lds[64][20];
  __shared__ float x_tile[32][16];
  int h = blockIdx.x / 100;
  int i0 = (blockIdx.x - h * 100) * 16;
  int t = threadIdx.x;
  for (int idx = t; idx < 6400; idx += 256) {
    int j = idx >> 6, d = idx & 63;
    v_lds[j][d] = v_t[(size_t)h * 6400 + idx];
  }
  for (int idx = t; idx < 512; idx += 256) {
    int ci = idx >> 4, i = idx & 15;
    x_tile[ci][i] = x[(h * 32 + ci) * NP + i0 + i];
  }
  __syncthreads();
  {
    int d = t & 63;
    int i4 = t >> 6;
    f32x4 wr[8];
#pragma unroll
    for (int qq = 0; qq < 8; ++qq)
      wr[qq] = *(const f32x4*)(wq + (size_t)(h * 64 + d) * 32 + qq * 4);
#pragma unroll
    for (int ii = 0; ii < 4; ++ii) {
      int i = i4 * 4 + ii;
      float acc = 0.f;
#pragma unroll
      for (int ci = 0; ci < 32; ++ci)
        acc = fmaf(wr[ci >> 2][ci & 3], x_tile[ci][i], acc);   // broadcast
      q_lds[d][i] = acc;
    }
  }
  __syncthreads();
  if (t < 200) {
    int ib = (t / 25) * 2, jb = (t % 25) * 4;
    const float* kp = k + h * 64 * 100 + jb;
    float a[2][4];
#pragma unroll
    for (int ii = 0; ii < 2; ++ii)
#pragma unroll
      for (int jj = 0; jj < 4; ++jj) a[ii][jj] = 0.f;
#pragma unroll 8
    for (int d = 0; d < 64; ++d) {
      f32x2 qv = *(const f32x2*)&q_lds[d][ib];
      f32x4 kv4 = *(const f32x4*)(kp + d * 100);
#pragma unroll
      for (int ii = 0; ii < 2; ++ii)
#pragma unroll
        for (int jj = 0; jj < 4; ++jj)
          a[ii][jj] = fmaf(qv[ii], kv4[jj], a[ii][jj]);
    }
    const _Float16* bcol = bias16 + (size_t)h * 100 * 1600;
#pragma unroll
    for (int jj = 0; jj < 4; ++jj) {
      f16x2 bv = *(const f16x2*)(bcol + (size_t)(jb + jj) * 1600 + i0 + ib);
#pragma unroll
      for (int ii = 0; ii < 2; ++ii)
        s_lds[ib + ii][jb + jj] = fmaf(a[ii][jj], 0.125f, (float)bv[ii]);
    }
  }
  __syncthreads();
  {
    int i = t >> 4, sub = t & 15;
    float m = -1e30f;
    for (int j = sub; j < 100; j += 16) m = fmaxf(m, s_lds[i][j]);
#pragma unroll
    for (int off = 1; off < 16; off <<= 1) m = fmaxf(m, __shfl_xor(m, off));
    float sum = 0.f;
    for (int j = sub; j < 100; j += 16) {
      float e = expf(s_lds[i][j] - m);
      s_lds[i][j] = e;
      sum += e;
    }
#pragma unroll
    for (int off = 1; off < 16; off <<= 1) sum += __shfl_xor(sum, off);
    float inv = 1.f / sum;
    for (int j = sub; j < 100; j += 16) s_lds[i][j] *= inv;
  }
  __syncthreads();
  {
    int i = t & 15, db = (t >> 4) * 4;
    float acc[4];
#pragma unroll
    for (int dd = 0; dd < 4; ++dd) acc[dd] = 0.f;
    for (int jc = 0; jc < 25; ++jc) {
      f32x4 sv = *(const f32x4*)&s_lds[i][jc * 4];
#pragma unroll
      for (int jj = 0; jj < 4; ++jj) {
        f32x4 vv = *(const f32x4*)&v_lds[jc * 4 + jj][db];
#pragma unroll
        for (int dd = 0; dd < 4; ++dd)
          acc[dd] = fmaf(sv[jj], vv[dd], acc[dd]);
      }
    }
#pragma unroll
    for (int dd = 0; dd < 4; ++dd)
      inner[(h * 64 + db + dd) * NP + i0 + i] = acc[dd];
  }
}

// ---------------- output projection: r12 structure (proven) ----------------
__global__ __launch_bounds__(256) void k_proj(
    const float* __restrict__ inner, const float* __restrict__ w,
    const float* __restrict__ bo, float* __restrict__ out) {
  int oc = blockIdx.x & 31;              // 32 o-chunks of 8
  int pt = blockIdx.x >> 5;              // 25 p-tiles of 64
  int t = threadIdx.x;
  int quad = __builtin_amdgcn_readfirstlane(t >> 6);  // wave-uniform
  int o0 = oc * 8 + quad * 2;
  int p = pt * 64 + (t & 63);
  const float* w0r = w + (size_t)o0 * 512;   // wave-uniform -> scalar loads
  float a0 = 0.f, a1 = 0.f;
#pragma unroll 8
  for (int c = 0; c < 512; ++c) {
    float xv = inner[c * NP + p];
    a0 = fmaf(w0r[c], xv, a0);
    a1 = fmaf(w0r[512 + c], xv, a1);
  }
  out[(o0 + 0) * NP + p] = a0 + bo[o0 + 0];
  out[(o0 + 1) * NP + p] = a1 + bo[o0 + 1];
}

extern "C" void kernel_launch(void* const* d_in, const int* in_sizes, int n_in,
                              void* d_out, int out_size, void* d_ws, size_t ws_size,
                              hipStream_t stream) {
  int L = in_sizes[1] / (512 * 32);
  int l = L - 1;
  const float* x      = (const float*)d_in[0];
  const float* wq     = (const float*)d_in[1]  + (size_t)l * 512 * 32;
  const float* wk     = (const float*)d_in[2]  + (size_t)l * 512 * 32;
  const float* wv     = (const float*)d_in[3]  + (size_t)l * 512 * 32;
  const float* w_off1 = (const float*)d_in[4]  + (size_t)l * 64 * 36;
  const float* b_off1 = (const float*)d_in[5]  + (size_t)l * 64;
  const float* w_off2 = (const float*)d_in[6]  + (size_t)l * 2 * 64;
  const float* cpb_w0 = (const float*)d_in[7]  + (size_t)l * 64 * 2;
  const float* cpb_b0 = (const float*)d_in[8]  + (size_t)l * 64;
  const float* cpb_w1 = (const float*)d_in[9]  + (size_t)l * 64 * 64;
  const float* cpb_b1 = (const float*)d_in[10] + (size_t)l * 64;
  const float* cpb_w2 = (const float*)d_in[11] + (size_t)l * 64;
  const float* cpb_b2 = (const float*)d_in[12] + (size_t)l * 1;
  const float* w_out  = (const float*)d_in[13] + (size_t)l * 256 * 512;
  const float* b_out  = (const float*)d_in[14] + (size_t)l * 256;
  float* out = (float*)d_out;

  float* ws = (float*)d_ws;
  float*    k_ws    = ws;               // 51200
  float*    vt_ws   = ws + 51200;       // 51200 (transposed [gj][c])
  _Float16* bias16  = (_Float16*)(ws + 102400);  // 1280000 halves = 640000 f
  float*    inner   = ws + 742400;      // 819200 ([c][p])  (end 6.25 MB)

  k_off_cpb<<<800, 256, 0, stream>>>(x, wq, w_off1, b_off1, w_off2, wk, wv,
                                     cpb_w0, cpb_b0, cpb_w1, cpb_b1, cpb_w2,
                                     cpb_b2, k_ws, vt_ws, bias16);
  k_attn<<<800, 256, 0, stream>>>(x, wq, k_ws, vt_ws, bias16, inner);
  k_proj<<<800, 256, 0, stream>>>(inner, w_out, b_out, out);
}